// Round 10
// baseline (187.328 us; speedup 1.0000x reference)
//
#include <hip/hip_runtime.h>
#include <math.h>

#define CIN   128
#define COUT  128
#define KKT   9
#define NSTAT 32768.0f   // B*H*W per-channel count

typedef __attribute__((ext_vector_type(8))) short bf16x8;
typedef __attribute__((ext_vector_type(4))) float f32x4;

__device__ inline unsigned short f2bf(float f) {
    union { float f; unsigned u; } v; v.f = f;
    unsigned r = v.u + 0x7fffu + ((v.u >> 16) & 1u);
    return (unsigned short)(r >> 16);
}
__device__ inline float bflo(unsigned u) { union { unsigned u; float f; } v; v.u = u << 16; return v.f; }
__device__ inline float bfhi(unsigned u) { union { unsigned u; float f; } v; v.u = u & 0xffff0000u; return v.f; }

// barrier that does NOT drain vmcnt
#define FAST_BARRIER() asm volatile("s_waitcnt lgkmcnt(0)\n\ts_barrier" ::: "memory")

// ---------------- ws layout (bytes) ----------------
// xt  : 16777216   bf16 channel-last x[b][y][x][c], dword c-pairs
// wb  : 294912     [oc][kt*128+c] bf16   (main conv A)
// wob : 73728      [32 ocpad][kt*128+c] bf16 (offset conv A, rows 18..31 zero)
// sums: 512 B      sums(128) | sumsq(128)

// Fused prep: blocks 0..511 transpose x -> xt; blocks 512+ repack weights + zero stats
__global__ __launch_bounds__(512) void prep_all_k(const float* __restrict__ x,
                                                  const float* __restrict__ w_def,
                                                  const float* __restrict__ w_off,
                                                  unsigned* __restrict__ xt,
                                                  unsigned short* __restrict__ wb,
                                                  unsigned short* __restrict__ wob,
                                                  float* __restrict__ sums) {
    const int blk = blockIdx.x;
    if (blk < 512) {
        __shared__ float lt[128][65];
        const int by = blk;              // b*64 + y
        const int b = by >> 6, y = by & 63;
        const int t = threadIdx.x, l = t & 63, g8 = t >> 6;
        const float* xb = x + (b * 128) * 4096 + y * 64;
#pragma unroll
        for (int pass = 0; pass < 16; pass++) {
            int c = pass * 8 + g8;
            lt[c][l] = xb[c * 4096 + l];
        }
        __syncthreads();
        unsigned* xo = xt + (by * 64) * 64;
#pragma unroll
        for (int pass = 0; pass < 8; pass++) {
            int w = pass * 8 + g8;
            float f0 = lt[2 * l][w], f1 = lt[2 * l + 1][w];
            xo[w * 64 + l] = (unsigned)f2bf(f0) | ((unsigned)f2bf(f1) << 16);
        }
    } else {
        int i = (blk - 512) * 512 + threadIdx.x;
        if (i < 147456) {
            int oc = i / 1152, r = i - oc * 1152, kt = r >> 7, c = r & 127;
            wb[i] = f2bf(w_def[(oc * 128 + c) * 9 + kt]);
        } else if (i < 147456 + 36864) {
            int j = i - 147456;
            int ocp = j / 1152, r = j - ocp * 1152, kt = r >> 7, c = r & 127;
            wob[j] = (ocp < 18) ? f2bf(w_off[(ocp * 128 + c) * 9 + kt]) : (unsigned short)0;
        } else if (i < 147456 + 36864 + 256) {
            sums[i - 147456 - 36864] = 0.f;
        }
    }
}

// One block per (b, h, half-row of 32 w). 1024 blocks x 512 threads.
// LDS ~29.4 KB + VGPR<=64 -> 4 blocks/CU (32 waves = HW cap): 4 independent
// barrier domains per CU vs R5's 2. Inner loop = R5's proven structure, halved.
__global__ __launch_bounds__(512, 8) void deform_main_k(const unsigned* __restrict__ xt,
                                                        const unsigned short* __restrict__ wb,
                                                        const unsigned short* __restrict__ wob,
                                                        const float* __restrict__ b_def,
                                                        float* __restrict__ out,
                                                        float* __restrict__ sums,
                                                        float* __restrict__ sumsq) {
    __shared__ __align__(16) unsigned char smem[29440];
    unsigned short* xrow  = (unsigned short*)smem;             // [3][34][128] bf16 = 26112 B (phase-0)
    int*            tab   = (int*)smem;                        // [9][32][8] dwords = 9216 B (aliases xrow)
    unsigned short* samp0 = (unsigned short*)(smem + 9216);    // [32][128] bf16 = 8192 B
    unsigned short* samp1 = (unsigned short*)(smem + 17408);   // 8192 B
    float* offl = (float*)(smem + 26112);                      // [18][32] = 2304 B
    float* stat = (float*)(smem + 28416);                      // [256] = 1024 B

    const int t    = threadIdx.x;
    const int bh   = blockIdx.x;
    const int b    = bh >> 7;
    const int r7   = bh & 127;
    const int j_   = r7 >> 1;
    const int half = r7 & 1;
    const int h    = ((j_ & 7) << 3) | (j_ >> 3);   // XCD-locality swizzle
    const int w0   = half * 32;                     // this block's w range: [w0, w0+32)
    const int lane = t & 63;
    const int wv   = __builtin_amdgcn_readfirstlane(t >> 6);  // 0..7
    const int quad = lane >> 4, lo = lane & 15;
    const int l    = lane;        // c-pair index for gathers
    const int g    = lane >> 2;   // c-group of 8

    if (t < 256) stat[t] = 0.f;

    const unsigned* xtb = xt + b * 262144;   // dwords per batch image

    // ---- stage xrow: rows h-1..h+1, x = w0-1 .. w0+32 (34 cols), zero-padded, swizzled ----
    for (int p = wv; p < 102; p += 8) {
        int r = p / 34, xi = p - r * 34;
        int y = h + r - 1, xp = w0 - 1 + xi;
        unsigned u = 0;
        if ((unsigned)y < 64u && (unsigned)xp < 64u) u = xtb[(y * 64 + xp) * 64 + l];
        ((unsigned*)xrow)[(r * 34 + xi) * 64 + ((g ^ (xi & 15)) << 2) + (l & 3)] = u;
    }
    __syncthreads();

    // ---- offset conv via MFMA from xrow: 4 tiles (2 M x 2 N), waves 0..3 ----
    if (wv < 4) {
        const int mt = wv >> 1, nt = wv & 1;
        const int wl = nt * 16 + lo;            // local w 0..31
        f32x4 ao = {0.f, 0.f, 0.f, 0.f};
        const unsigned short* wrow = wob + (mt * 16 + lo) * 1152 + quad * 8;
        for (int kt = 0; kt < 9; kt++) {
            int ky = kt / 3, kx = kt - ky * 3;
            int xi = wl + kx;                   // xrow col: x = w0-1+xi = (w0+wl) + kx - 1
#pragma unroll
            for (int ch = 0; ch < 4; ch++) {
                int gg = ch * 4 + quad;
                bf16x8 af = *(const bf16x8*)(wrow + kt * 128 + ch * 32);
                bf16x8 bf = *(const bf16x8*)(xrow + (ky * 34 + xi) * 128 + ((gg ^ (xi & 15)) << 3));
                ao = __builtin_amdgcn_mfma_f32_16x16x32_bf16(af, bf, ao, 0, 0, 0);
            }
        }
        __syncthreads();   // all waves done reading xrow
#pragma unroll
        for (int r = 0; r < 4; r++) {
            int oc = mt * 16 + quad * 4 + r;
            if (oc < 18) offl[oc * 32 + wl] = ao[r];
        }
    } else {
        __syncthreads();
    }
    __syncthreads();   // offl ready; xrow region free for tab

    // ---- tap tables: [9][32] entries ----
    for (int i = t; i < KKT * 32; i += 512) {
        int k = i >> 5, w2l = i & 31;
        int w2g = w0 + w2l;
        float dy = offl[(2 * k) * 32 + w2l];
        float dx = offl[(2 * k + 1) * 32 + w2l];
        int ky = k / 3, kx = k - ky * 3;
        float ys = (float)(h - 1 + ky) + dy;
        float xs = (float)(w2g - 1 + kx) + dx;
        float y0f = floorf(ys), x0f = floorf(xs);
        float wyf = ys - y0f, wxf = xs - x0f;
        int iy0 = (int)y0f, ix0 = (int)x0f;
        int cy0 = min(max(iy0, 0), 63), cy1 = min(max(iy0 + 1, 0), 63);
        int px  = min(max(ix0, 0), 63), px2 = min(max(ix0 + 1, 0), 63);
        float wy0 = (iy0 >= 0 && iy0 < 64) ? (1.f - wyf) : 0.f;
        float wy1 = (iy0 + 1 >= 0 && iy0 + 1 < 64) ? wyf : 0.f;
        float wa  = (ix0 >= 0 && ix0 < 64) ? (1.f - wxf) : 0.f;
        float wbv = (ix0 + 1 >= 0 && ix0 + 1 < 64) ? wxf : 0.f;
        int base = i * 8;
        tab[base + 0] = (cy0 * 64 + px ) * 64;
        tab[base + 1] = (cy0 * 64 + px2) * 64;
        tab[base + 2] = (cy1 * 64 + px ) * 64;
        tab[base + 3] = (cy1 * 64 + px2) * 64;
        ((float*)tab)[base + 4] = wy0;
        ((float*)tab)[base + 5] = wy1;
        ((float*)tab)[base + 6] = wa;
        ((float*)tab)[base + 7] = wbv;
    }
    __syncthreads();

    // ---- tap loop (R5 structure, half-width): coalesced gathers + dbuf samp + MFMA ----
    const int m0 = wv >> 1, n0 = wv & 1;   // M-tiles {2m0,2m0+1}, N-tile n0 (16 w)
    f32x4 acc[2];
#pragma unroll
    for (int i = 0; i < 2; i++)
#pragma unroll
        for (int r = 0; r < 4; r++) acc[i][r] = 0.f;

    const unsigned short* wrow0 = wb + (2 * m0 * 16 + lo) * 1152 + quad * 8;
    const unsigned short* wrow1 = wrow0 + 16 * 1152;

    for (int kt = 0; kt < KKT; kt++) {
        bf16x8 af0[4], af1[4];
#pragma unroll
        for (int ch = 0; ch < 4; ch++) {
            af0[ch] = *(const bf16x8*)(wrow0 + kt * 128 + ch * 32);
            af1[ch] = *(const bf16x8*)(wrow1 + kt * 128 + ch * 32);
        }
        // gather: wave covers local w = wv*4 .. wv*4+3; lane = c-pair -> coalesced
        unsigned* sb = (unsigned*)((kt & 1) ? samp1 : samp0);
#pragma unroll
        for (int i = 0; i < 4; i++) {
            int wl = wv * 4 + i;
            int bse = (kt * 32 + wl) * 8;
            int4   ta = *(const int4*)&tab[bse];        // wave-uniform LDS broadcast
            float4 tw = *(const float4*)&tab[bse + 4];
            unsigned u00 = xtb[ta.x + l];
            unsigned u01 = xtb[ta.y + l];
            unsigned u10 = xtb[ta.z + l];
            unsigned u11 = xtb[ta.w + l];
            float e = tw.x * (tw.z * bflo(u00) + tw.w * bflo(u01)) +
                      tw.y * (tw.z * bflo(u10) + tw.w * bflo(u11));
            float o = tw.x * (tw.z * bfhi(u00) + tw.w * bfhi(u01)) +
                      tw.y * (tw.z * bfhi(u10) + tw.w * bfhi(u11));
            sb[wl * 64 + ((g ^ (wl & 15)) << 2) + (l & 3)] =
                (unsigned)f2bf(e) | ((unsigned)f2bf(o) << 16);
        }
        FAST_BARRIER();
        const unsigned short* sbs = (kt & 1) ? samp1 : samp0;
#pragma unroll
        for (int ch = 0; ch < 4; ch++) {
            int gg = ch * 4 + quad;
            int r0 = n0 * 16 + lo;
            bf16x8 bf0 = *(const bf16x8*)(sbs + r0 * 128 + ((gg ^ lo) << 3));
            acc[0] = __builtin_amdgcn_mfma_f32_16x16x32_bf16(af0[ch], bf0, acc[0], 0, 0, 0);
            acc[1] = __builtin_amdgcn_mfma_f32_16x16x32_bf16(af1[ch], bf0, acc[1], 0, 0, 0);
        }
    }

    // ---- epilogue: bias + store pre-BN + fused BN stats ----
    float* ob = out + b * COUT * 4096 + h * 64;
    const int w_ = w0 + n0 * 16 + lo;
#pragma unroll
    for (int mt2 = 0; mt2 < 2; mt2++) {
        int ocb = (2 * m0 + mt2) * 16 + quad * 4;
#pragma unroll
        for (int r = 0; r < 4; r++) {
            int oc = ocb + r;
            float v = acc[mt2][r] + b_def[oc];
            ob[oc * 4096 + w_] = v;
            float ssum = v, qsum = v * v;
#pragma unroll
            for (int d = 1; d < 16; d <<= 1) {
                ssum += __shfl_xor(ssum, d, 64);
                qsum += __shfl_xor(qsum, d, 64);
            }
            if (lo == 0) { atomicAdd(&stat[oc], ssum); atomicAdd(&stat[128 + oc], qsum); }
        }
    }
    __syncthreads();
    if (t < 256) {
        float* gp = (t < 128) ? (sums + t) : (sumsq + (t - 128));
        atomicAdd(gp, stat[t]);
    }
}

__global__ __launch_bounds__(256) void bn_silu_k(float* __restrict__ out,
                                                 const float* __restrict__ sums,
                                                 const float* __restrict__ sumsq,
                                                 const float* __restrict__ gamma,
                                                 const float* __restrict__ beta) {
    __shared__ float sc_s[128], sh_s[128];
    int t = threadIdx.x;
    if (t < 128) {
        const float invN = 1.f / NSTAT;
        float m = sums[t] * invN;
        float v = fmaf(-m, m, sumsq[t] * invN);
        float sc = gamma[t] * rsqrtf(v + 1e-5f);
        sc_s[t] = sc;
        sh_s[t] = beta[t] - m * sc;
    }
    __syncthreads();
    int i = blockIdx.x * 256 + t;
    float4 v = ((float4*)out)[i];
    int oc = (i >> 10) & 127;
    float sc = sc_s[oc], sh = sh_s[oc];
    float z0 = v.x * sc + sh;
    float z1 = v.y * sc + sh;
    float z2 = v.z * sc + sh;
    float z3 = v.w * sc + sh;
    v.x = z0 / (1.f + __expf(-z0));
    v.y = z1 / (1.f + __expf(-z1));
    v.z = z2 / (1.f + __expf(-z2));
    v.w = z3 / (1.f + __expf(-z3));
    ((float4*)out)[i] = v;
}

extern "C" void kernel_launch(void* const* d_in, const int* in_sizes, int n_in,
                              void* d_out, int out_size, void* d_ws, size_t ws_size,
                              hipStream_t stream) {
    const float* x     = (const float*)d_in[0];
    const float* w_off = (const float*)d_in[1];
    const float* w_def = (const float*)d_in[2];
    const float* b_def = (const float*)d_in[3];
    const float* gamma = (const float*)d_in[4];
    const float* beta  = (const float*)d_in[5];
    float* out = (float*)d_out;

    unsigned*       xt   = (unsigned*)d_ws;                               // 16777216 B
    unsigned short* wb   = (unsigned short*)((char*)d_ws + 16777216);     // 294912 B
    unsigned short* wob  = (unsigned short*)((char*)d_ws + 17072128);     // 73728 B
    float*          sums = (float*)((char*)d_ws + 17145856);              // 128
    float*          sumsq = sums + 128;

    prep_all_k<<<873, 512, 0, stream>>>(x, w_def, w_off, xt, wb, wob, sums);
    deform_main_k<<<1024, 512, 0, stream>>>(xt, wb, wob, b_def, out, sums, sumsq);
    bn_silu_k<<<4096, 256, 0, stream>>>(out, sums, sumsq, gamma, beta);
}